// Round 1
// baseline (413.644 us; speedup 1.0000x reference)
//
#include <hip/hip_runtime.h>
#include <hip/hip_cooperative_groups.h>
#include <math.h>

namespace cg = cooperative_groups;

#define D_ 128
#define NTOK 8192
#define CHUNK 64
#define NCB 64        // chunks per batch
#define NCH 128       // total chunks
#define LN_EPS 1e-5f
#define EPS_ATTN 1e-6f
#define NBLK 512

typedef __attribute__((ext_vector_type(8))) short bf16x8;
typedef __attribute__((ext_vector_type(4))) short bf16x4;
typedef __attribute__((ext_vector_type(2))) short bf16x2;
typedef __attribute__((ext_vector_type(4))) float f32x4;

__device__ inline short f2bf(float f) {
  unsigned u = __builtin_bit_cast(unsigned, f);
  u += 0x7fffu + ((u >> 16) & 1u);
  return (short)(u >> 16);
}
__device__ inline float bf2f(short s) {
  unsigned u = ((unsigned)(unsigned short)s) << 16;
  return __builtin_bit_cast(float, u);
}
__device__ inline float phi_(float x) { return x > 0.f ? x + 1.f : __expf(x); }

// Single cooperative kernel.  512 blocks x 256 thr, 2 blocks/CU resident
// (launch_bounds(256,2) caps VGPR<=256; LDS union 62720B -> >=2/CU).
// P0 wprep | P1 LN1+QKVG | P2 intra-scores + chunk KV^T | P3 prefix scans |
// P4 attn num/den | P5 residual + Wo + LN2.   5 grid.sync() boundaries.
__global__ __launch_bounds__(256, 2) void k_mega(
    const float* __restrict__ tokens,
    const float* __restrict__ Wq, const float* __restrict__ Wk,
    const float* __restrict__ Wv, const float* __restrict__ Wg,
    const float* __restrict__ bgp, const float* __restrict__ Wo,
    const float* __restrict__ g1, const float* __restrict__ b1,
    const float* __restrict__ g2, const float* __restrict__ b2,
    float* __restrict__ out, char* __restrict__ ws)
{
  cg::grid_group grid = cg::this_grid();
  const int tid = threadIdx.x;
  const int bid = blockIdx.x;

  short* Qp     = (short*)(ws);
  short* Kp     = (short*)(ws + (2u<<20));
  short* KpT    = (short*)(ws + (4u<<20));
  short* VgT    = (short*)(ws + (6u<<20));
  short* attnb  = (short*)(ws + (8u<<20));
  short* KVTb   = (short*)(ws + (10u<<20));
  short* Aintra = (short*)(ws + (14u<<20));
  short* WT     = (short*)(ws + (15u<<20));
  float* rowsum = (float*)(ws + (15u<<20) + (256u<<10));
  float* Ksum   = (float*)(ws + (15u<<20) + (512u<<10));
  float* KVT    = (float*)(ws + (16u<<20));

  __shared__ __align__(16) char smem[62720];

  const int w = tid >> 6, l = tid & 63;
  const int i = l & 15, q = l >> 4;

  // ================= P0: weights fp32 [k][n] -> bf16 [n][k] (10 half-mat units) =================
  if (bid < 10) {
    const int mat = bid >> 1, half = bid & 1;
    const float* W = mat==0?Wq: mat==1?Wk: mat==2?Wv: mat==3?Wg:Wo;
    short* o = WT + mat*D_*D_;
    float (*lds)[132] = (float(*)[132])smem;   // 64 x 132 fp32 = 33792B
    #pragma unroll
    for (int it = 0; it < 8; ++it) {
      const int f = it*1024 + tid*4;
      const int kk = f >> 7, n = f & 127;
      const float4 v = *(const float4*)&W[(half*64 + kk)*D_ + n];
      lds[kk][n] = v.x; lds[kk][n+1] = v.y; lds[kk][n+2] = v.z; lds[kk][n+3] = v.w;
    }
    __syncthreads();
    #pragma unroll
    for (int it = 0; it < 8; ++it) {
      const int f = it*1024 + tid*4;
      const int n = f >> 6, kl = f & 63;
      bf16x4 ov;
      ov.x = f2bf(lds[kl][n]);   ov.y = f2bf(lds[kl+1][n]);
      ov.z = f2bf(lds[kl+2][n]); ov.w = f2bf(lds[kl+3][n]);
      *(bf16x4*)&o[n*D_ + half*64 + kl] = ov;
    }
  }
  grid.sync();

  // ================= P1: LN1 + QKVG GEMMs (768 tile-units, role-per-block, W staged once) =================
  {
    short (*xs)[136]  = (short(*)[136])smem;           // 32 x 136
    short (*wsd)[136] = (short(*)[136])(smem + 8704);  // 128 x 136

    auto stageW = [&](const short* __restrict__ Wb) {
      for (int v = tid; v < 2048; v += 256) {
        const int n = v >> 4, c8 = (v & 15)*8;
        *(bf16x8*)&wsd[n][c8] = *(const bf16x8*)&Wb[n*D_ + c8];
      }
    };
    auto doLN = [&](int m0) {
      const float2 gg = *(const float2*)&g1[l*2];
      const float2 bb = *(const float2*)&b1[l*2];
      float2 tv[8];
      #pragma unroll
      for (int it = 0; it < 8; ++it)
        tv[it] = *(const float2*)&tokens[(m0 + w*8 + it)*D_ + l*2];
      #pragma unroll
      for (int it = 0; it < 8; ++it) {
        const float2 v = tv[it];
        float s = v.x + v.y, qq = v.x*v.x + v.y*v.y;
        #pragma unroll
        for (int off = 1; off < 64; off <<= 1) {
          s += __shfl_xor(s, off); qq += __shfl_xor(qq, off);
        }
        const float mean = s*(1.f/D_);
        const float r2 = rsqrtf(qq*(1.f/D_) - mean*mean + LN_EPS);
        bf16x2 o;
        o.x = f2bf((v.x-mean)*r2*gg.x + bb.x);
        o.y = f2bf((v.y-mean)*r2*gg.y + bb.y);
        *(bf16x2*)&xs[w*8 + it][l*2] = o;
      }
    };
    auto gemm = [&](f32x4 (*acc)[2]) {
      #pragma unroll
      for (int kk = 0; kk < 4; ++kk) {
        bf16x8 a[2], bfr[2];
        #pragma unroll
        for (int mt = 0; mt < 2; ++mt) a[mt] = *(const bf16x8*)&xs[mt*16+i][kk*32+q*8];
        #pragma unroll
        for (int nt = 0; nt < 2; ++nt) bfr[nt] = *(const bf16x8*)&wsd[w*32+nt*16+i][kk*32+q*8];
        #pragma unroll
        for (int mt = 0; mt < 2; ++mt)
          #pragma unroll
          for (int nt = 0; nt < 2; ++nt)
            acc[mt][nt] = __builtin_amdgcn_mfma_f32_16x16x32_bf16(a[mt], bfr[nt], acc[mt][nt], 0, 0, 0);
      }
    };

    if (bid < 256) {
      // ---- V + G tile (2 GEMMs, heavy) : one tile per block ----
      const int m0 = bid * 32;
      doLN(m0);
      stageW(WT + 2*D_*D_);          // Wv^T
      __syncthreads();
      f32x4 acc[2][2], accg[2][2];
      #pragma unroll
      for (int mt = 0; mt < 2; ++mt)
        #pragma unroll
        for (int nt = 0; nt < 2; ++nt) acc[mt][nt] = (f32x4){0.f,0.f,0.f,0.f};
      gemm(acc);
      __syncthreads();
      stageW(WT + 3*D_*D_);          // Wg^T
      __syncthreads();
      #pragma unroll
      for (int mt = 0; mt < 2; ++mt)
        #pragma unroll
        for (int nt = 0; nt < 2; ++nt) accg[mt][nt] = (f32x4){0.f,0.f,0.f,0.f};
      gemm(accg);
      #pragma unroll
      for (int mt = 0; mt < 2; ++mt)
        #pragma unroll
        for (int nt = 0; nt < 2; ++nt) {
          const int h = w*32 + nt*16 + i;
          const int t0 = m0 + mt*16 + 4*q;
          const float bgd = bgp[h];
          bf16x4 o;
          #pragma unroll
          for (int r = 0; r < 4; ++r) {
            const float gv = 1.f/(1.f + __expf(-(accg[mt][nt][r] + bgd)));
            o[r] = f2bf(acc[mt][nt][r] * gv);
          }
          *(bf16x4*)&VgT[h*NTOK + t0] = o;
        }
    } else if (bid < 384) {
      // ---- Q tiles x2, Wq staged once ----
      stageW(WT);
      for (int uu = 0; uu < 2; ++uu) {
        const int m0 = ((bid - 256)*2 + uu) * 32;
        __syncthreads();
        doLN(m0);
        __syncthreads();
        f32x4 acc[2][2];
        #pragma unroll
        for (int mt = 0; mt < 2; ++mt)
          #pragma unroll
          for (int nt = 0; nt < 2; ++nt) acc[mt][nt] = (f32x4){0.f,0.f,0.f,0.f};
        gemm(acc);
        #pragma unroll
        for (int mt = 0; mt < 2; ++mt)
          #pragma unroll
          for (int nt = 0; nt < 2; ++nt) {
            const int h = w*32 + nt*16 + i;
            #pragma unroll
            for (int r = 0; r < 4; ++r)
              Qp[(m0 + mt*16 + 4*q + r)*D_ + h] = f2bf(phi_(acc[mt][nt][r]));
          }
      }
    } else {
      // ---- K tiles x2, Wk staged once ----
      stageW(WT + D_*D_);
      for (int uu = 0; uu < 2; ++uu) {
        const int m0 = ((bid - 384)*2 + uu) * 32;
        __syncthreads();
        doLN(m0);
        __syncthreads();
        f32x4 acc[2][2];
        #pragma unroll
        for (int mt = 0; mt < 2; ++mt)
          #pragma unroll
          for (int nt = 0; nt < 2; ++nt) acc[mt][nt] = (f32x4){0.f,0.f,0.f,0.f};
        gemm(acc);
        #pragma unroll
        for (int mt = 0; mt < 2; ++mt)
          #pragma unroll
          for (int nt = 0; nt < 2; ++nt) {
            const int h = w*32 + nt*16 + i;
            const int t0 = m0 + mt*16 + 4*q;
            bf16x4 o;
            #pragma unroll
            for (int r = 0; r < 4; ++r) {
              const short bv = f2bf(phi_(acc[mt][nt][r]));
              Kp[(t0+r)*D_ + h] = bv;
              o[r] = bv;
            }
            *(bf16x4*)&KpT[h*NTOK + t0] = o;
          }
      }
    }
  }
  grid.sync();

  // ================= P2: intra-chunk scores (128 units) + chunk KV^T quarters (512 units) =================
  {
    auto chunkkv = [&](int v) {
      const int c = v & 127, hh = (v >> 7) & 1, dh = v >> 8;
      const int tb = c*CHUNK;
      short (*vgl)[72] = (short(*)[72])smem;             // 64 x 72
      short (*kpl)[72] = (short(*)[72])(smem + 9216);    // 64 x 72
      float (*ksp)[5]  = (float(*)[5])(smem + 18432);    // 64 x 5
      for (int u = tid; u < 512; u += 256) {
        const int dd = u >> 3, c8 = (u & 7)*8;
        *(bf16x8*)&vgl[dd][c8] = *(const bf16x8*)&VgT[(dh*64+dd)*NTOK + tb + c8];
        *(bf16x8*)&kpl[dd][c8] = *(const bf16x8*)&KpT[(hh*64+dd)*NTOK + tb + c8];
      }
      __syncthreads();
      f32x4 acc[4];
      #pragma unroll
      for (int nt = 0; nt < 4; ++nt) acc[nt] = (f32x4){0.f,0.f,0.f,0.f};
      #pragma unroll
      for (int kk = 0; kk < 2; ++kk) {
        bf16x8 a = *(const bf16x8*)&vgl[w*16+i][kk*32+q*8];
        #pragma unroll
        for (int nt = 0; nt < 4; ++nt) {
          bf16x8 bb = *(const bf16x8*)&kpl[nt*16+i][kk*32+q*8];
          acc[nt] = __builtin_amdgcn_mfma_f32_16x16x32_bf16(a, bb, acc[nt], 0, 0, 0);
        }
      }
      float* KVc = KVT + (size_t)c*16384;
      #pragma unroll
      for (int nt = 0; nt < 4; ++nt)
        #pragma unroll
        for (int r = 0; r < 4; ++r) {
          const int d = dh*64 + w*16 + 4*q + r;
          const int h = hh*64 + nt*16 + i;
          KVc[d*D_ + h] = acc[nt][r];
        }
      if (dh == 0) {
        const int hq = tid >> 2, part = tid & 3;
        float s = 0.f;
        #pragma unroll
        for (int t = 0; t < 16; ++t) s += bf2f(kpl[hq][part*16 + t]);
        ksp[hq][part] = s;
        __syncthreads();
        if (tid < 64)
          Ksum[c*D_ + hh*64 + tid] = ksp[tid][0]+ksp[tid][1]+ksp[tid][2]+ksp[tid][3];
      }
    };

    auto scores = [&](int c) {
      const int tb = c*CHUNK;
      short (*qpl)[136] = (short(*)[136])smem;            // 64 x 136
      short (*kpl)[136] = (short(*)[136])(smem + 17408);  // 64 x 136
      for (int u = tid; u < 1024; u += 256) {
        const int t = u >> 4, c8 = (u & 15)*8;
        *(bf16x8*)&qpl[t][c8] = *(const bf16x8*)&Qp[(tb+t)*D_ + c8];
        *(bf16x8*)&kpl[t][c8] = *(const bf16x8*)&Kp[(tb+t)*D_ + c8];
      }
      __syncthreads();
      f32x4 acc[4];
      #pragma unroll
      for (int nt = 0; nt < 4; ++nt) acc[nt] = (f32x4){0.f,0.f,0.f,0.f};
      #pragma unroll
      for (int kk = 0; kk < 4; ++kk) {
        bf16x8 a = *(const bf16x8*)&qpl[w*16+i][kk*32+q*8];
        #pragma unroll
        for (int nt = 0; nt < 4; ++nt) {
          if (nt <= w) {   // wave-uniform predicate, static acc index (no scratch)
            bf16x8 bb = *(const bf16x8*)&kpl[nt*16+i][kk*32+q*8];
            acc[nt] = __builtin_amdgcn_mfma_f32_16x16x32_bf16(a, bb, acc[nt], 0, 0, 0);
          }
        }
      }
      short* Ac = Aintra + c*4096;
      float rs[4] = {0.f,0.f,0.f,0.f};
      #pragma unroll
      for (int nt = 0; nt < 4; ++nt) {
        #pragma unroll
        for (int r = 0; r < 4; ++r) {
          const int t = w*16 + 4*q + r;
          const int s = nt*16 + i;
          const float v = (nt <= w && s <= t) ? acc[nt][r] : 0.f;
          rs[r] += v;
          Ac[t*64 + s] = f2bf(v);
        }
      }
      #pragma unroll
      for (int r = 0; r < 4; ++r) {
        #pragma unroll
        for (int off = 1; off < 16; off <<= 1) rs[r] += __shfl_xor(rs[r], off);
      }
      if (i == 0) {
        #pragma unroll
        for (int r = 0; r < 4; ++r) rowsum[c*64 + w*16 + 4*q + r] = rs[r];
      }
    };

    if (bid < 128) {
      scores(bid);
      __syncthreads();
      chunkkv(384 + bid);      // (c=bid, hh=1, dh=1)
    } else {
      chunkkv(bid - 128);      // units 0..383
    }
  }
  grid.sync();

  // ================= P3: prefix scans (KVT over chunks; Ksum over chunks) =================
  {
    if (bid < 128) {
      const int b = bid >> 6;
      const int e = (bid & 63)*256 + tid;
      const size_t basei = (size_t)b*NCB*16384 + e;
      float run = 0.f;
      #pragma unroll 8
      for (int c = 0; c < NCB; ++c) {
        const float v = KVT[basei + (size_t)c*16384];
        KVTb[basei + (size_t)c*16384] = f2bf(run);
        run += v;
      }
    } else if (bid == 128) {
      const int b = tid >> 7, h = tid & 127;
      float run = 0.f;
      #pragma unroll 8
      for (int c = 0; c < NCB; ++c) {
        const int idx = (b*NCB + c)*128 + h;
        const float v = Ksum[idx];
        Ksum[idx] = run;
        run += v;
      }
    }
  }
  grid.sync();

  // ================= P4: num/den + attn, d-quarters (512 units) =================
  {
    const int c = bid & 127, dq = bid >> 7;
    const int tb = c*CHUNK;
    short (*at)[200] = (short(*)[200])smem;              // 64 x 200
    short (*bt)[200] = (short(*)[200])(smem + 25600);    // 32 x 200
    float* ksl        = (float*)(smem + 38400);          // 128
    float (*dpart)[4] = (float(*)[4])(smem + 38912);     // 64 x 4
    float* denl       = (float*)(smem + 39936);          // 64
    const short* Ac = Aintra + c*4096;
    for (int u = tid; u < 512; u += 256) {
      const int t = u >> 3, c8 = (u & 7)*8;
      *(bf16x8*)&at[t][c8] = *(const bf16x8*)&Ac[t*64 + c8];
    }
    for (int u = tid; u < 1024; u += 256) {
      const int t = u >> 4, c8 = (u & 15)*8;
      *(bf16x8*)&at[t][64 + c8] = *(const bf16x8*)&Qp[(tb+t)*D_ + c8];
    }
    for (int u = tid; u < 256; u += 256) {
      const int dd = u >> 3, c8 = (u & 7)*8;
      *(bf16x8*)&bt[dd][c8] = *(const bf16x8*)&VgT[(dq*32+dd)*NTOK + tb + c8];
    }
    for (int u = tid; u < 512; u += 256) {
      const int dd = u >> 4, c8 = (u & 15)*8;
      *(bf16x8*)&bt[dd][64 + c8] = *(const bf16x8*)&KVTb[(size_t)c*16384 + (dq*32+dd)*D_ + c8];
    }
    if (tid < 128) ksl[tid] = Ksum[c*128 + tid];
    __syncthreads();
    {
      const int t = tid >> 2, part = tid & 3;
      float dot = 0.f;
      #pragma unroll
      for (int h = 0; h < 32; ++h) dot += bf2f(at[t][64 + part*32 + h]) * ksl[part*32 + h];
      dpart[t][part] = dot;
    }
    __syncthreads();
    if (tid < 64)
      denl[tid] = fmaxf(rowsum[c*64 + tid] + dpart[tid][0]+dpart[tid][1]+dpart[tid][2]+dpart[tid][3], EPS_ATTN);
    __syncthreads();
    f32x4 acc[2];
    #pragma unroll
    for (int nt = 0; nt < 2; ++nt) acc[nt] = (f32x4){0.f,0.f,0.f,0.f};
    #pragma unroll
    for (int kk = 0; kk < 6; ++kk) {
      bf16x8 a = *(const bf16x8*)&at[w*16+i][kk*32+q*8];
      #pragma unroll
      for (int nt = 0; nt < 2; ++nt) {
        bf16x8 bb = *(const bf16x8*)&bt[nt*16+i][kk*32+q*8];
        acc[nt] = __builtin_amdgcn_mfma_f32_16x16x32_bf16(a, bb, acc[nt], 0, 0, 0);
      }
    }
    #pragma unroll
    for (int r = 0; r < 4; ++r) {
      const int t = w*16 + 4*q + r;
      const float inv = 1.f / denl[t];
      #pragma unroll
      for (int nt = 0; nt < 2; ++nt)
        attnb[(size_t)(tb+t)*D_ + dq*32 + nt*16 + i] = f2bf(acc[nt][r] * inv);
    }
  }
  grid.sync();

  // ================= P5: out = LN2(tokens + 0.1*(attn@Wo)), 32-token tiles (256 units) =================
  if (bid < 256) {
    const int m0 = bid * 32;
    short (*al)[136] = (short(*)[136])smem;             // 32 x 136
    short (*wl)[136] = (short(*)[136])(smem + 8704);    // 128 x 136
    float (*tl)[132] = (float(*)[132])(smem + 43520);   // 32 x 132
    float (*suml)[4] = (float(*)[4])(smem + 60416);
    float (*ssql)[4] = (float(*)[4])(smem + 60928);
    float* meanl = (float*)(smem + 61440);
    float* rstdl = (float*)(smem + 61568);
    float* gl    = (float*)(smem + 61696);
    float* bl2   = (float*)(smem + 62208);
    const short* WoT = WT + 4*D_*D_;

    for (int u = tid; u < 512; u += 256) {
      const int t = u >> 4, c8 = (u & 15)*8;
      *(bf16x8*)&al[t][c8] = *(const bf16x8*)&attnb[(m0+t)*D_ + c8];
    }
    for (int u = tid; u < 2048; u += 256) {
      const int n = u >> 4, c8 = (u & 15)*8;
      *(bf16x8*)&wl[n][c8] = *(const bf16x8*)&WoT[n*D_ + c8];
    }
    for (int u = tid; u < 1024; u += 256) {
      const int t = u >> 5, c4 = (u & 31)*4;
      *(float4*)&tl[t][c4] = *(const float4*)&tokens[(m0+t)*D_ + c4];
    }
    if (tid < 128) { gl[tid] = g2[tid]; bl2[tid] = b2[tid]; }
    __syncthreads();

    f32x4 acc[2][2];
    #pragma unroll
    for (int mt = 0; mt < 2; ++mt)
      #pragma unroll
      for (int j = 0; j < 2; ++j) acc[mt][j] = (f32x4){0.f,0.f,0.f,0.f};
    #pragma unroll
    for (int kk = 0; kk < 4; ++kk) {
      bf16x8 a[2];
      #pragma unroll
      for (int mt = 0; mt < 2; ++mt) a[mt] = *(const bf16x8*)&al[mt*16+i][kk*32+q*8];
      #pragma unroll
      for (int j = 0; j < 2; ++j) {
        bf16x8 bb = *(const bf16x8*)&wl[(w*2+j)*16+i][kk*32+q*8];
        #pragma unroll
        for (int mt = 0; mt < 2; ++mt)
          acc[mt][j] = __builtin_amdgcn_mfma_f32_16x16x32_bf16(a[mt], bb, acc[mt][j], 0, 0, 0);
      }
    }
    float p[2][4][2];
    #pragma unroll
    for (int mt = 0; mt < 2; ++mt)
      #pragma unroll
      for (int r = 0; r < 4; ++r) {
        const int t = mt*16 + 4*q + r;
        float ps = 0.f, qs = 0.f;
        #pragma unroll
        for (int j = 0; j < 2; ++j) {
          const int col = w*32 + j*16 + i;
          const float v = tl[t][col] + 0.1f*acc[mt][j][r];
          p[mt][r][j] = v; ps += v; qs += v*v;
        }
        #pragma unroll
        for (int off = 1; off < 16; off <<= 1) {
          ps += __shfl_xor(ps, off); qs += __shfl_xor(qs, off);
        }
        if (i == 0) { suml[t][w] = ps; ssql[t][w] = qs; }
      }
    __syncthreads();
    if (tid < 32) {
      const float s = suml[tid][0]+suml[tid][1]+suml[tid][2]+suml[tid][3];
      const float qq = ssql[tid][0]+ssql[tid][1]+ssql[tid][2]+ssql[tid][3];
      const float mean = s*(1.f/D_);
      meanl[tid] = mean;
      rstdl[tid] = rsqrtf(qq*(1.f/D_) - mean*mean + LN_EPS);
    }
    __syncthreads();
    #pragma unroll
    for (int mt = 0; mt < 2; ++mt)
      #pragma unroll
      for (int r = 0; r < 4; ++r) {
        const int t = mt*16 + 4*q + r;
        const float mean = meanl[t], rr = rstdl[t];
        #pragma unroll
        for (int j = 0; j < 2; ++j) {
          const int col = w*32 + j*16 + i;
          out[(m0+t)*D_ + col] = (p[mt][r][j]-mean)*rr*gl[col] + bl2[col];
        }
      }
  }
}

extern "C" void kernel_launch(void* const* d_in, const int* in_sizes, int n_in,
                              void* d_out, int out_size, void* d_ws, size_t ws_size,
                              hipStream_t stream) {
  const float* tokens = (const float*)d_in[0];
  const float* Wq = (const float*)d_in[1];
  const float* Wk = (const float*)d_in[2];
  const float* Wv = (const float*)d_in[3];
  const float* Wg = (const float*)d_in[4];
  const float* bg = (const float*)d_in[5];
  const float* Wo = (const float*)d_in[6];
  const float* g1 = (const float*)d_in[7];
  const float* b1 = (const float*)d_in[8];
  const float* g2 = (const float*)d_in[9];
  const float* b2 = (const float*)d_in[10];
  float* outp = (float*)d_out;
  char* wsp = (char*)d_ws;

  void* args[] = { (void*)&tokens, (void*)&Wq, (void*)&Wk, (void*)&Wv, (void*)&Wg,
                   (void*)&bg, (void*)&Wo, (void*)&g1, (void*)&b1, (void*)&g2,
                   (void*)&b2, (void*)&outp, (void*)&wsp };
  hipLaunchCooperativeKernel((const void*)k_mega, dim3(NBLK), dim3(256), args, 0, stream);
}

// Round 2
// 112.637 us; speedup vs baseline: 3.6724x; 3.6724x over previous
//
#include <hip/hip_runtime.h>
#include <math.h>

#define D_ 128
#define NTOK 8192
#define CHUNK 64
#define NCB 64        // chunks per batch
#define NCH 128       // total chunks
#define LN_EPS 1e-5f
#define EPS_ATTN 1e-6f

typedef __attribute__((ext_vector_type(8))) short bf16x8;
typedef __attribute__((ext_vector_type(4))) short bf16x4;
typedef __attribute__((ext_vector_type(2))) short bf16x2;
typedef __attribute__((ext_vector_type(4))) float f32x4;

__device__ inline short f2bf(float f) {
  unsigned u = __builtin_bit_cast(unsigned, f);
  u += 0x7fffu + ((u >> 16) & 1u);
  return (short)(u >> 16);
}
__device__ inline float bf2f(short s) {
  unsigned u = ((unsigned)(unsigned short)s) << 16;
  return __builtin_bit_cast(float, u);
}
__device__ inline float phi_(float x) { return x > 0.f ? x + 1.f : __expf(x); }

// ============ K0: weight transpose (10 half-mat units) + LN1 -> xln bf16 (256 tiles) ============
__global__ __launch_bounds__(256) void k_prep(const float* __restrict__ tokens,
    const float* __restrict__ Wq, const float* __restrict__ Wk,
    const float* __restrict__ Wv, const float* __restrict__ Wg,
    const float* __restrict__ Wo,
    const float* __restrict__ g1, const float* __restrict__ b1,
    short* __restrict__ WT, short* __restrict__ xln) {
  const int tid = threadIdx.x, bid = blockIdx.x;
  __shared__ float lds[64][132];
  if (bid < 10) {
    const int mat = bid >> 1, half = bid & 1;
    const float* W = mat==0?Wq: mat==1?Wk: mat==2?Wv: mat==3?Wg:Wo;
    short* o = WT + mat*D_*D_;
    #pragma unroll
    for (int it = 0; it < 8; ++it) {
      const int f = it*1024 + tid*4;
      const int kk = f >> 7, n = f & 127;
      const float4 v = *(const float4*)&W[(half*64 + kk)*D_ + n];
      lds[kk][n] = v.x; lds[kk][n+1] = v.y; lds[kk][n+2] = v.z; lds[kk][n+3] = v.w;
    }
    __syncthreads();
    #pragma unroll
    for (int it = 0; it < 8; ++it) {
      const int f = it*1024 + tid*4;
      const int n = f >> 6, kl = f & 63;
      bf16x4 ov;
      ov.x = f2bf(lds[kl][n]);   ov.y = f2bf(lds[kl+1][n]);
      ov.z = f2bf(lds[kl+2][n]); ov.w = f2bf(lds[kl+3][n]);
      *(bf16x4*)&o[n*D_ + half*64 + kl] = ov;
    }
    return;
  }
  // ---- LN1 for 32 tokens per block ----
  const int m0 = (bid - 10) * 32;
  const int w = tid >> 6, l = tid & 63;
  const float2 gg = *(const float2*)&g1[l*2];
  const float2 bb = *(const float2*)&b1[l*2];
  float2 tv[8];
  #pragma unroll
  for (int it = 0; it < 8; ++it)
    tv[it] = *(const float2*)&tokens[(m0 + w*8 + it)*D_ + l*2];
  #pragma unroll
  for (int it = 0; it < 8; ++it) {
    const float2 v = tv[it];
    float s = v.x + v.y, qq = v.x*v.x + v.y*v.y;
    #pragma unroll
    for (int off = 1; off < 64; off <<= 1) {
      s += __shfl_xor(s, off); qq += __shfl_xor(qq, off);
    }
    const float mean = s*(1.f/D_);
    const float r2 = rsqrtf(qq*(1.f/D_) - mean*mean + LN_EPS);
    bf16x2 o;
    o.x = f2bf((v.x-mean)*r2*gg.x + bb.x);
    o.y = f2bf((v.y-mean)*r2*gg.y + bb.y);
    *(bf16x2*)&xln[(m0 + w*8 + it)*D_ + l*2] = o;
  }
}

// ============ K1: QKVG GEMMs, role-per-block (512 blocks) ============
// bid<256: V+G (1 tile, 2 GEMMs); [256,384): Q x2 tiles; [384,512): K x2 tiles
__global__ __launch_bounds__(256) void k_qkvg(const short* __restrict__ xln,
    const short* __restrict__ WT, const float* __restrict__ bgp,
    short* __restrict__ Qp, short* __restrict__ Kp, short* __restrict__ KpT,
    short* __restrict__ VgT) {
  const int tid = threadIdx.x, bid = blockIdx.x;
  const int w = tid >> 6, l = tid & 63;
  const int i = l & 15, q = l >> 4;
  __shared__ short xs[32][136];
  __shared__ short wsd[128][136];

  auto stageW = [&](const short* __restrict__ Wb) {
    for (int v = tid; v < 2048; v += 256) {
      const int n = v >> 4, c8 = (v & 15)*8;
      *(bf16x8*)&wsd[n][c8] = *(const bf16x8*)&Wb[n*D_ + c8];
    }
  };
  auto stageX = [&](int m0) {
    for (int u = tid; u < 512; u += 256) {
      const int t = u >> 4, c8 = (u & 15)*8;
      *(bf16x8*)&xs[t][c8] = *(const bf16x8*)&xln[(m0 + t)*D_ + c8];
    }
  };
  auto gemm = [&](f32x4 (*acc)[2]) {
    #pragma unroll
    for (int kk = 0; kk < 4; ++kk) {
      bf16x8 a[2], bfr[2];
      #pragma unroll
      for (int mt = 0; mt < 2; ++mt) a[mt] = *(const bf16x8*)&xs[mt*16+i][kk*32+q*8];
      #pragma unroll
      for (int nt = 0; nt < 2; ++nt) bfr[nt] = *(const bf16x8*)&wsd[w*32+nt*16+i][kk*32+q*8];
      #pragma unroll
      for (int mt = 0; mt < 2; ++mt)
        #pragma unroll
        for (int nt = 0; nt < 2; ++nt)
          acc[mt][nt] = __builtin_amdgcn_mfma_f32_16x16x32_bf16(a[mt], bfr[nt], acc[mt][nt], 0, 0, 0);
    }
  };

  if (bid < 256) {
    const int m0 = bid * 32;
    stageX(m0);
    stageW(WT + 2*D_*D_);          // Wv^T
    __syncthreads();
    f32x4 acc[2][2], accg[2][2];
    #pragma unroll
    for (int mt = 0; mt < 2; ++mt)
      #pragma unroll
      for (int nt = 0; nt < 2; ++nt) acc[mt][nt] = (f32x4){0.f,0.f,0.f,0.f};
    gemm(acc);
    __syncthreads();
    stageW(WT + 3*D_*D_);          // Wg^T
    __syncthreads();
    #pragma unroll
    for (int mt = 0; mt < 2; ++mt)
      #pragma unroll
      for (int nt = 0; nt < 2; ++nt) accg[mt][nt] = (f32x4){0.f,0.f,0.f,0.f};
    gemm(accg);
    #pragma unroll
    for (int mt = 0; mt < 2; ++mt)
      #pragma unroll
      for (int nt = 0; nt < 2; ++nt) {
        const int h = w*32 + nt*16 + i;
        const int t0 = m0 + mt*16 + 4*q;
        const float bgd = bgp[h];
        bf16x4 o;
        #pragma unroll
        for (int r = 0; r < 4; ++r) {
          const float gv = 1.f/(1.f + __expf(-(accg[mt][nt][r] + bgd)));
          o[r] = f2bf(acc[mt][nt][r] * gv);
        }
        *(bf16x4*)&VgT[h*NTOK + t0] = o;
      }
  } else if (bid < 384) {
    stageW(WT);                    // Wq^T
    for (int uu = 0; uu < 2; ++uu) {
      const int m0 = ((bid - 256)*2 + uu) * 32;
      __syncthreads();
      stageX(m0);
      __syncthreads();
      f32x4 acc[2][2];
      #pragma unroll
      for (int mt = 0; mt < 2; ++mt)
        #pragma unroll
        for (int nt = 0; nt < 2; ++nt) acc[mt][nt] = (f32x4){0.f,0.f,0.f,0.f};
      gemm(acc);
      #pragma unroll
      for (int mt = 0; mt < 2; ++mt)
        #pragma unroll
        for (int nt = 0; nt < 2; ++nt) {
          const int h = w*32 + nt*16 + i;
          #pragma unroll
          for (int r = 0; r < 4; ++r)
            Qp[(m0 + mt*16 + 4*q + r)*D_ + h] = f2bf(phi_(acc[mt][nt][r]));
        }
    }
  } else {
    stageW(WT + D_*D_);            // Wk^T
    for (int uu = 0; uu < 2; ++uu) {
      const int m0 = ((bid - 384)*2 + uu) * 32;
      __syncthreads();
      stageX(m0);
      __syncthreads();
      f32x4 acc[2][2];
      #pragma unroll
      for (int mt = 0; mt < 2; ++mt)
        #pragma unroll
        for (int nt = 0; nt < 2; ++nt) acc[mt][nt] = (f32x4){0.f,0.f,0.f,0.f};
      gemm(acc);
      #pragma unroll
      for (int mt = 0; mt < 2; ++mt)
        #pragma unroll
        for (int nt = 0; nt < 2; ++nt) {
          const int h = w*32 + nt*16 + i;
          const int t0 = m0 + mt*16 + 4*q;
          bf16x4 o;
          #pragma unroll
          for (int r = 0; r < 4; ++r) {
            const short bv = f2bf(phi_(acc[mt][nt][r]));
            Kp[(t0+r)*D_ + h] = bv;
            o[r] = bv;
          }
          *(bf16x4*)&KpT[h*NTOK + t0] = o;
        }
    }
  }
}

// ============ K2: intra-chunk scores (128 units) + chunk KV^T quarters (512 units) in 512 blocks ============
__global__ __launch_bounds__(256) void k_cs(const short* __restrict__ KpT,
    const short* __restrict__ VgT, const short* __restrict__ Qp,
    const short* __restrict__ Kp,
    float* __restrict__ KVT, float* __restrict__ Ksum,
    short* __restrict__ A, float* __restrict__ rowsum) {
  const int tid = threadIdx.x, bid = blockIdx.x;
  const int w = tid >> 6, l = tid & 63;
  const int i = l & 15, q = l >> 4;
  __shared__ __align__(16) char smem[34816];

  auto chunkkv = [&](int v) {
    const int c = v & 127, hh = (v >> 7) & 1, dh = v >> 8;
    const int tb = c*CHUNK;
    short (*vgl)[72] = (short(*)[72])smem;             // 64 x 72
    short (*kpl)[72] = (short(*)[72])(smem + 9216);    // 64 x 72
    float (*ksp)[5]  = (float(*)[5])(smem + 18432);    // 64 x 5
    for (int u = tid; u < 512; u += 256) {
      const int dd = u >> 3, c8 = (u & 7)*8;
      *(bf16x8*)&vgl[dd][c8] = *(const bf16x8*)&VgT[(dh*64+dd)*NTOK + tb + c8];
      *(bf16x8*)&kpl[dd][c8] = *(const bf16x8*)&KpT[(hh*64+dd)*NTOK + tb + c8];
    }
    __syncthreads();
    f32x4 acc[4];
    #pragma unroll
    for (int nt = 0; nt < 4; ++nt) acc[nt] = (f32x4){0.f,0.f,0.f,0.f};
    #pragma unroll
    for (int kk = 0; kk < 2; ++kk) {
      bf16x8 a = *(const bf16x8*)&vgl[w*16+i][kk*32+q*8];
      #pragma unroll
      for (int nt = 0; nt < 4; ++nt) {
        bf16x8 bb = *(const bf16x8*)&kpl[nt*16+i][kk*32+q*8];
        acc[nt] = __builtin_amdgcn_mfma_f32_16x16x32_bf16(a, bb, acc[nt], 0, 0, 0);
      }
    }
    float* KVc = KVT + (size_t)c*16384;
    #pragma unroll
    for (int nt = 0; nt < 4; ++nt)
      #pragma unroll
      for (int r = 0; r < 4; ++r) {
        const int d = dh*64 + w*16 + 4*q + r;
        const int h = hh*64 + nt*16 + i;
        KVc[d*D_ + h] = acc[nt][r];
      }
    if (dh == 0) {
      const int hq = tid >> 2, part = tid & 3;
      float s = 0.f;
      #pragma unroll
      for (int t = 0; t < 16; ++t) s += bf2f(kpl[hq][part*16 + t]);
      ksp[hq][part] = s;
      __syncthreads();
      if (tid < 64)
        Ksum[c*D_ + hh*64 + tid] = ksp[tid][0]+ksp[tid][1]+ksp[tid][2]+ksp[tid][3];
    }
  };

  auto scores = [&](int c) {
    const int tb = c*CHUNK;
    short (*qpl)[136] = (short(*)[136])smem;            // 64 x 136
    short (*kpl)[136] = (short(*)[136])(smem + 17408);  // 64 x 136
    for (int u = tid; u < 1024; u += 256) {
      const int t = u >> 4, c8 = (u & 15)*8;
      *(bf16x8*)&qpl[t][c8] = *(const bf16x8*)&Qp[(tb+t)*D_ + c8];
      *(bf16x8*)&kpl[t][c8] = *(const bf16x8*)&Kp[(tb+t)*D_ + c8];
    }
    __syncthreads();
    f32x4 acc[4];
    #pragma unroll
    for (int nt = 0; nt < 4; ++nt) acc[nt] = (f32x4){0.f,0.f,0.f,0.f};
    #pragma unroll
    for (int kk = 0; kk < 4; ++kk) {
      bf16x8 a = *(const bf16x8*)&qpl[w*16+i][kk*32+q*8];
      #pragma unroll
      for (int nt = 0; nt < 4; ++nt) {
        if (nt <= w) {
          bf16x8 bb = *(const bf16x8*)&kpl[nt*16+i][kk*32+q*8];
          acc[nt] = __builtin_amdgcn_mfma_f32_16x16x32_bf16(a, bb, acc[nt], 0, 0, 0);
        }
      }
    }
    short* Ac = A + c*4096;
    float rs[4] = {0.f,0.f,0.f,0.f};
    #pragma unroll
    for (int nt = 0; nt < 4; ++nt) {
      #pragma unroll
      for (int r = 0; r < 4; ++r) {
        const int t = w*16 + 4*q + r;
        const int s = nt*16 + i;
        const float v = (nt <= w && s <= t) ? acc[nt][r] : 0.f;
        rs[r] += v;
        Ac[t*64 + s] = f2bf(v);
      }
    }
    #pragma unroll
    for (int r = 0; r < 4; ++r) {
      #pragma unroll
      for (int off = 1; off < 16; off <<= 1) rs[r] += __shfl_xor(rs[r], off);
    }
    if (i == 0) {
      #pragma unroll
      for (int r = 0; r < 4; ++r) rowsum[c*64 + w*16 + 4*q + r] = rs[r];
    }
  };

  if (bid < 128) {
    scores(bid);
    __syncthreads();
    chunkkv(384 + bid);      // (c=bid, hh=1, dh=1)
  } else {
    chunkkv(bid - 128);      // units 0..383
  }
}

// ============ K3: prefix scans (129 blocks) ============
__global__ __launch_bounds__(256) void k_scan(const float* __restrict__ KVT,
    short* __restrict__ KVTb, float* __restrict__ Ksum) {
  const int tid = threadIdx.x;
  if (blockIdx.x < 128) {
    const int b = blockIdx.x >> 6;
    const int e = (blockIdx.x & 63)*256 + tid;
    const size_t base = (size_t)b*NCB*16384 + e;
    float run = 0.f;
    #pragma unroll 8
    for (int c = 0; c < NCB; ++c) {
      const float v = KVT[base + (size_t)c*16384];
      KVTb[base + (size_t)c*16384] = f2bf(run);
      run += v;
    }
    return;
  }
  const int b = tid >> 7, h = tid & 127;
  float run = 0.f;
  #pragma unroll 8
  for (int c = 0; c < NCB; ++c) {
    const int idx = (b*NCB + c)*128 + h;
    const float v = Ksum[idx];
    Ksum[idx] = run;
    run += v;
  }
}

// ============ K4: num/den + attn, d-quarters (512 blocks) ============
__global__ __launch_bounds__(256) void k_attnout(const short* __restrict__ Aintra,
    const short* __restrict__ Qp, const short* __restrict__ VgT,
    const short* __restrict__ KVTb, const float* __restrict__ Ksum,
    const float* __restrict__ rowsum, short* __restrict__ attn) {
  const int bid = blockIdx.x, tid = threadIdx.x;
  const int c = bid & 127, dq = bid >> 7;
  const int tb = c*CHUNK;
  __shared__ short at[64][200], bt[32][200];
  __shared__ float ksl[128], dpart[64][4], denl[64];
  const short* Ac = Aintra + c*4096;
  #pragma unroll
  for (int u = tid; u < 512; u += 256) {
    const int t = u >> 3, c8 = (u & 7)*8;
    *(bf16x8*)&at[t][c8] = *(const bf16x8*)&Ac[t*64 + c8];
  }
  #pragma unroll
  for (int u = tid; u < 1024; u += 256) {
    const int t = u >> 4, c8 = (u & 15)*8;
    *(bf16x8*)&at[t][64 + c8] = *(const bf16x8*)&Qp[(tb+t)*D_ + c8];
  }
  for (int u = tid; u < 256; u += 256) {
    const int dd = u >> 3, c8 = (u & 7)*8;
    *(bf16x8*)&bt[dd][c8] = *(const bf16x8*)&VgT[(dq*32+dd)*NTOK + tb + c8];
  }
  #pragma unroll
  for (int u = tid; u < 512; u += 256) {
    const int dd = u >> 4, c8 = (u & 15)*8;
    *(bf16x8*)&bt[dd][64 + c8] = *(const bf16x8*)&KVTb[(size_t)c*16384 + (dq*32+dd)*D_ + c8];
  }
  if (tid < 128) ksl[tid] = Ksum[c*128 + tid];
  __syncthreads();
  {
    const int t = tid >> 2, part = tid & 3;
    float dot = 0.f;
    #pragma unroll
    for (int h = 0; h < 32; ++h) dot += bf2f(at[t][64 + part*32 + h]) * ksl[part*32 + h];
    dpart[t][part] = dot;
  }
  __syncthreads();
  if (tid < 64)
    denl[tid] = fmaxf(rowsum[c*64 + tid] + dpart[tid][0]+dpart[tid][1]+dpart[tid][2]+dpart[tid][3], EPS_ATTN);
  __syncthreads();
  const int w = tid >> 6, l = tid & 63, i = l & 15, q = l >> 4;
  f32x4 acc[2];
  #pragma unroll
  for (int nt = 0; nt < 2; ++nt) acc[nt] = (f32x4){0.f,0.f,0.f,0.f};
  #pragma unroll
  for (int kk = 0; kk < 6; ++kk) {
    bf16x8 a = *(const bf16x8*)&at[w*16+i][kk*32+q*8];
    #pragma unroll
    for (int nt = 0; nt < 2; ++nt) {
      bf16x8 bb = *(const bf16x8*)&bt[nt*16+i][kk*32+q*8];
      acc[nt] = __builtin_amdgcn_mfma_f32_16x16x32_bf16(a, bb, acc[nt], 0, 0, 0);
    }
  }
  #pragma unroll
  for (int r = 0; r < 4; ++r) {
    const int t = w*16 + 4*q + r;
    const float inv = 1.f / denl[t];
    #pragma unroll
    for (int nt = 0; nt < 2; ++nt)
      attn[(size_t)(tb+t)*D_ + dq*32 + nt*16 + i] = f2bf(acc[nt][r] * inv);
  }
}

// ============ K5: out = LN2(tokens + 0.1*(attn@Wo)), 32-token tiles (256 blocks) ============
__global__ __launch_bounds__(256) void k_outln2(const short* __restrict__ attn,
    const short* __restrict__ WoT, const float* __restrict__ tokens,
    const float* __restrict__ g2, const float* __restrict__ b2,
    float* __restrict__ out) {
  const int m0 = blockIdx.x*32, tid = threadIdx.x;
  __shared__ short al[32][136], wl[128][136];
  __shared__ float tl[32][132];
  __shared__ float suml[32][4], ssql[32][4];
  __shared__ float meanl[32], rstdl[32];
  __shared__ float gl[128], bl2[128];
  for (int u = tid; u < 512; u += 256) {
    const int t = u >> 4, c8 = (u & 15)*8;
    *(bf16x8*)&al[t][c8] = *(const bf16x8*)&attn[(m0+t)*D_ + c8];
  }
  #pragma unroll
  for (int u = tid; u < 2048; u += 256) {
    const int n = u >> 4, c8 = (u & 15)*8;
    *(bf16x8*)&wl[n][c8] = *(const bf16x8*)&WoT[n*D_ + c8];
  }
  #pragma unroll
  for (int u = tid; u < 1024; u += 256) {
    const int t = u >> 5, c4 = (u & 31)*4;
    *(float4*)&tl[t][c4] = *(const float4*)&tokens[(m0+t)*D_ + c4];
  }
  if (tid < 128) { gl[tid] = g2[tid]; bl2[tid] = b2[tid]; }
  __syncthreads();
  const int w = tid >> 6, l = tid & 63, i = l & 15, q = l >> 4;
  f32x4 acc[2][2];
  #pragma unroll
  for (int mt = 0; mt < 2; ++mt)
    #pragma unroll
    for (int j = 0; j < 2; ++j) acc[mt][j] = (f32x4){0.f,0.f,0.f,0.f};
  #pragma unroll
  for (int kk = 0; kk < 4; ++kk) {
    bf16x8 a[2];
    #pragma unroll
    for (int mt = 0; mt < 2; ++mt) a[mt] = *(const bf16x8*)&al[mt*16+i][kk*32+q*8];
    #pragma unroll
    for (int j = 0; j < 2; ++j) {
      bf16x8 bb = *(const bf16x8*)&wl[(w*2+j)*16+i][kk*32+q*8];
      #pragma unroll
      for (int mt = 0; mt < 2; ++mt)
        acc[mt][j] = __builtin_amdgcn_mfma_f32_16x16x32_bf16(a[mt], bb, acc[mt][j], 0, 0, 0);
    }
  }
  float p[2][4][2];
  #pragma unroll
  for (int mt = 0; mt < 2; ++mt)
    #pragma unroll
    for (int r = 0; r < 4; ++r) {
      const int t = mt*16 + 4*q + r;
      float ps = 0.f, qs = 0.f;
      #pragma unroll
      for (int j = 0; j < 2; ++j) {
        const int col = w*32 + j*16 + i;
        const float v = tl[t][col] + 0.1f*acc[mt][j][r];
        p[mt][r][j] = v; ps += v; qs += v*v;
      }
      #pragma unroll
      for (int off = 1; off < 16; off <<= 1) {
        ps += __shfl_xor(ps, off); qs += __shfl_xor(qs, off);
      }
      if (i == 0) { suml[t][w] = ps; ssql[t][w] = qs; }
    }
  __syncthreads();
  if (tid < 32) {
    const float s = suml[tid][0]+suml[tid][1]+suml[tid][2]+suml[tid][3];
    const float qq = ssql[tid][0]+ssql[tid][1]+ssql[tid][2]+ssql[tid][3];
    const float mean = s*(1.f/D_);
    meanl[tid] = mean;
    rstdl[tid] = rsqrtf(qq*(1.f/D_) - mean*mean + LN_EPS);
  }
  __syncthreads();
  #pragma unroll
  for (int mt = 0; mt < 2; ++mt)
    #pragma unroll
    for (int r = 0; r < 4; ++r) {
      const int t = mt*16 + 4*q + r;
      const float mean = meanl[t], rr = rstdl[t];
      #pragma unroll
      for (int j = 0; j < 2; ++j) {
        const int col = w*32 + j*16 + i;
        out[(m0+t)*D_ + col] = (p[mt][r][j]-mean)*rr*gl[col] + bl2[col];
      }
    }
}

extern "C" void kernel_launch(void* const* d_in, const int* in_sizes, int n_in,
                              void* d_out, int out_size, void* d_ws, size_t ws_size,
                              hipStream_t stream) {
  const float* tokens = (const float*)d_in[0];
  const float* Wq = (const float*)d_in[1];
  const float* Wk = (const float*)d_in[2];
  const float* Wv = (const float*)d_in[3];
  const float* Wg = (const float*)d_in[4];
  const float* bg = (const float*)d_in[5];
  const float* Wo = (const float*)d_in[6];
  const float* g1 = (const float*)d_in[7];
  const float* b1 = (const float*)d_in[8];
  const float* g2 = (const float*)d_in[9];
  const float* b2 = (const float*)d_in[10];

  char* base = (char*)d_ws;
  short* Qp     = (short*)(base);                        // 2MB
  short* Kp     = (short*)(base + (2u<<20));             // 2MB
  short* KpT    = (short*)(base + (4u<<20));             // 2MB
  short* VgT    = (short*)(base + (6u<<20));             // 2MB
  short* attn   = (short*)(base + (8u<<20));             // 2MB
  short* KVTb   = (short*)(base + (10u<<20));            // 4MB
  short* Aintra = (short*)(base + (14u<<20));            // 1MB
  short* WT     = (short*)(base + (15u<<20));            // 160KB (5 mats)
  float* rowsum = (float*)(base + (15u<<20) + (256u<<10)); // 32KB
  float* Ksum   = (float*)(base + (15u<<20) + (512u<<10)); // 64KB
  float* KVT    = (float*)(base + (16u<<20));            // 8MB
  short* xln    = (short*)(base + (24u<<20));            // 2MB

  short* WoT = WT + 4*D_*D_;

  k_prep<<<266, 256, 0, stream>>>(tokens, Wq, Wk, Wv, Wg, Wo, g1, b1, WT, xln);
  k_qkvg<<<512, 256, 0, stream>>>(xln, WT, bg, Qp, Kp, KpT, VgT);
  k_cs<<<512, 256, 0, stream>>>(KpT, VgT, Qp, Kp, KVT, Ksum, Aintra, rowsum);
  k_scan<<<129, 256, 0, stream>>>(KVT, KVTb, Ksum);
  k_attnout<<<512, 256, 0, stream>>>(Aintra, Qp, VgT, KVTb, Ksum, rowsum, attn);
  k_outln2<<<NTOK/32, 256, 0, stream>>>(attn, WoT, tokens, g2, b2, (float*)d_out);
}